// Round 3
// baseline (540.574 us; speedup 1.0000x reference)
//
#include <hip/hip_runtime.h>
#include <math.h>

// B=64, N=512, T=6, H=4, E=256, hd=64 ; BN=32768 chunks
#define TT 6
#define HH 4
#define EE 256
#define RB 16            // chunks per block
#define PR 8             // chunks per phase-A pass
#define NTHREADS 256

typedef __attribute__((ext_vector_type(8))) short bf16x8;
typedef __attribute__((ext_vector_type(4))) float f32x4;

__device__ __forceinline__ unsigned short f2b(float f) {
    union { float f; unsigned u; } v; v.f = f;
    unsigned u = v.u + 0x7fffu + ((v.u >> 16) & 1u);
    return (unsigned short)(u >> 16);
}
__device__ __forceinline__ float b2f(unsigned short s) {
    union { unsigned u; float f; } v; v.u = ((unsigned)s) << 16;
    return v.f;
}

// Split 8 contiguous fp32 into (hi=trunc-bf16, lo=rn-bf16 of residual) fragments.
// hi+lo reconstructs v to ~2^-17 relative.
__device__ __forceinline__ void split8(const float* __restrict__ p,
                                       bf16x8& hi, bf16x8& lo) {
    float4 a = *(const float4*)p;
    float4 b = *(const float4*)(p + 4);
    float f[8] = {a.x, a.y, a.z, a.w, b.x, b.y, b.z, b.w};
    union { unsigned short s[8]; bf16x8 v; } H, L;
#pragma unroll
    for (int i = 0; i < 8; ++i) {
        union { float f; unsigned u; } t; t.f = f[i];
        unsigned short h = (unsigned short)(t.u >> 16);   // truncation hi
        H.s[i] = h;
        L.s[i] = f2b(f[i] - b2f(h));
    }
    hi = H.v; lo = L.v;
}

// ---------------- workspace layout (bytes) ----------------
//   swt_hi [4][256] bf16 @ 0     (score weights, hi)
//   swt_lo [4][256] bf16 @ 2048  (score weights, lo)
//   sb     [4]  f32      @ 4096  (q_h . bk_h)
//   total 4112 bytes — tiny, no OOB risk.
#define SWTH_OFF 0
#define SWTL_OFF 2048
#define SB_OFF   4096

// ---- setup: q = query @ Wq^T + bq ; sb[h] = q_h . bk_h ; swt = fold(q, Wk) (1 block) ----
__global__ void setup_q(const float* __restrict__ query,
                        const float* __restrict__ in_proj_w,
                        const float* __restrict__ in_proj_b,
                        unsigned char* __restrict__ ws)
{
    __shared__ float qs[EE];
    unsigned short* swth = (unsigned short*)(ws + SWTH_OFF);
    unsigned short* swtl = (unsigned short*)(ws + SWTL_OFF);
    float* sb = (float*)(ws + SB_OFF);
    const int tid = threadIdx.x;
    float acc = in_proj_b[tid];
    const float* row = in_proj_w + (size_t)tid * EE;
    for (int e = 0; e < EE; e += 4) {
        float4 w = *(const float4*)(row + e);
        float4 q = *(const float4*)(query + e);
        acc += w.x * q.x + w.y * q.y + w.z * q.z + w.w * q.w;
    }
    qs[tid] = acc;
    __syncthreads();
    if (tid < HH) {
        float a = 0.f;
        for (int d = 0; d < 64; ++d) a += qs[tid * 64 + d] * in_proj_b[EE + tid * 64 + d];
        sb[tid] = a;
    }
    // swt[n][k] = sum_d q[n*64+d] * Wk[n*64+d][k], split hi/lo (RN split)
#pragma unroll
    for (int n = 0; n < HH; ++n) {
        float a = 0.f;
        for (int d = 0; d < 64; ++d)
            a += qs[n * 64 + d] * in_proj_w[(size_t)(EE + n * 64 + d) * EE + tid];
        unsigned short h = f2b(a);
        swth[n * EE + tid] = h;
        swtl[n * EE + tid] = f2b(a - b2f(h));
    }
}

// ---------------- main fused kernel ----------------
// LDS pool layout (bytes):
#define XS_OFF   0        // xs   [48][260] bf16 = 24960 (x hi; phase A, dead after scores of last pass)
#define XBH_OFF  24960    // xb8h [8][1028] bf16 = 16448 (per-pass xbar hi)
#define XBL_OFF  41408    // xb8l [8][1028] bf16 = 16448 (per-pass xbar lo)
#define YPH_OFF  57856    // yph  [16][260] bf16 = 8320  (ypre hi, persists B1->B2)
#define YPL_OFF  66176    // ypl  [16][260] bf16 = 8320
#define SCF_OFF  74496    // scf  [48][5] f32 = 960
#define AW_OFF   75456    // aw4  [8][6][4] f32 = 768
#define VAL_OFF  76224    // validf [16] f32 = 64
#define MB_OFF   76288    // mbuf [48] int = 192
#define POOL_SZ  76480
// aliases:
//   xsl (x lo, [48][260] bf16 = 24960) aliases XBH..XBL region (24960..49920 < 57856):
//     live load->scores, while xbh/xbl live xbar->B1 (2 barriers apart). safe.
#define XSL_OFF  24960
// after phase A:
#define OUTV_OFF 0        // outv [16][260] f32 = 16640 (xs region)
#define LNH_OFF  24960    // lnh  [16][260] bf16 = 8320 (xbh region)
#define LNL_OFF  33280    // lnl  [16][260] bf16 = 8320
#define HB_OFF   41600    // hbf  [16][132] f32 = 8448  (ends 50048, xbl region)

__global__ __launch_bounds__(NTHREADS, 2)
void fused_head_kernel(const float* __restrict__ x,
                       const int* __restrict__ mask,
                       const float* __restrict__ in_proj_w,
                       const float* __restrict__ in_proj_b,
                       const float* __restrict__ out_w,
                       const float* __restrict__ out_b,
                       const float* __restrict__ ln_g,
                       const float* __restrict__ ln_b,
                       const float* __restrict__ w1,
                       const float* __restrict__ b1,
                       const float* __restrict__ w2,
                       const float* __restrict__ b2,
                       const unsigned char* __restrict__ ws,
                       float* __restrict__ out)
{
    __shared__ __align__(16) unsigned char pool[POOL_SZ];
    unsigned short* xs   = (unsigned short*)(pool + XS_OFF);
    unsigned short* xsl  = (unsigned short*)(pool + XSL_OFF);
    unsigned short* xbh  = (unsigned short*)(pool + XBH_OFF);
    unsigned short* xbl  = (unsigned short*)(pool + XBL_OFF);
    unsigned short* yph  = (unsigned short*)(pool + YPH_OFF);
    unsigned short* ypl  = (unsigned short*)(pool + YPL_OFF);
    float*          scf  = (float*)(pool + SCF_OFF);
    float*          aw4  = (float*)(pool + AW_OFF);
    float*          vldf = (float*)(pool + VAL_OFF);
    int*            mbuf = (int*)(pool + MB_OFF);
    float*          outv = (float*)(pool + OUTV_OFF);
    unsigned short* lnh  = (unsigned short*)(pool + LNH_OFF);
    unsigned short* lnl  = (unsigned short*)(pool + LNL_OFF);
    float*          hbf  = (float*)(pool + HB_OFF);

    const unsigned short* swth = (const unsigned short*)(ws + SWTH_OFF);
    const unsigned short* swtl = (const unsigned short*)(ws + SWTL_OFF);
    const float*          sb   = (const float*)(ws + SB_OFF);
    const float*          wvw  = in_proj_w + (size_t)(2 * EE) * EE;  // Wv (fp32)

    const int tid = threadIdx.x;
    const int wv  = tid >> 6;
    const int ln  = tid & 63;
    const int qd  = ln >> 4;        // quad 0..3
    const int nl  = ln & 15;        // m/n lane 0..15
    const int eh  = tid & 63;       // e-column group (e = eh*4) for load/xbar
    const int gq2 = tid >> 6;       // chunk-pair group for load/xbar
    const int chunk0 = blockIdx.x * RB;

    float4 xv[2][TT];               // this thread's fp32 x slice (2 chunks x 6 t x 4 cols)

    // ================= Phase A + per-pass B1 (two passes of 8 chunks) =================
    for (int p = 0; p < 2; ++p) {
        const int c0 = chunk0 + p * PR;
        __syncthreads();   // xs/xsl / mbuf / aw4 / scf / xb8 reuse safe
        if (tid < PR * TT) mbuf[tid] = mask[(size_t)c0 * TT + tid];
        // ---- load x -> registers (fp32) and xs/xsl (hi/lo bf16 for score MFMA)
        const float* xp = x + (size_t)c0 * (TT * EE);
#pragma unroll
        for (int gi = 0; gi < 2; ++gi) {
#pragma unroll
            for (int t = 0; t < TT; ++t) {
                const int r = (gq2 * 2 + gi) * TT + t;
                float4 v = *(const float4*)(xp + r * EE + eh * 4);
                xv[gi][t] = v;
                union { unsigned short u[4]; uint2 v2; } th, tl;
                th.u[0] = f2b(v.x); tl.u[0] = f2b(v.x - b2f(th.u[0]));
                th.u[1] = f2b(v.y); tl.u[1] = f2b(v.y - b2f(th.u[1]));
                th.u[2] = f2b(v.z); tl.u[2] = f2b(v.z - b2f(th.u[2]));
                th.u[3] = f2b(v.w); tl.u[3] = f2b(v.w - b2f(th.u[3]));
                *(uint2*)(xs  + r * 260 + eh * 4) = th.v2;
                *(uint2*)(xsl + r * 260 + eh * 4) = tl.v2;
            }
        }
        __syncthreads();
        // ---- scores MFMA (hi/lo both sides): S[(g,t)][h] ; 3 M-tiles over 48 rows
        if (wv < 3) {
            const int mt = wv;
            f32x4 acc = {0.f, 0.f, 0.f, 0.f};
            for (int kb = 0; kb < EE; kb += 32) {
                bf16x8 ah = *(const bf16x8*)(xs  + (mt * 16 + nl) * 260 + kb + qd * 8);
                bf16x8 al = *(const bf16x8*)(xsl + (mt * 16 + nl) * 260 + kb + qd * 8);
                bf16x8 bh = *(const bf16x8*)(swth + (nl & 3) * EE + kb + qd * 8);
                bf16x8 bl = *(const bf16x8*)(swtl + (nl & 3) * EE + kb + qd * 8);
                acc = __builtin_amdgcn_mfma_f32_16x16x32_bf16(ah, bh, acc, 0, 0, 0);
                acc = __builtin_amdgcn_mfma_f32_16x16x32_bf16(al, bh, acc, 0, 0, 0);
                acc = __builtin_amdgcn_mfma_f32_16x16x32_bf16(ah, bl, acc, 0, 0, 0);
            }
            if (nl < HH) {
#pragma unroll
                for (int i = 0; i < 4; ++i)
                    scf[(mt * 16 + qd * 4 + i) * 5 + nl] = acc[i];
            }
        }
        __syncthreads();
        // ---- softmax (tid<32: (g,h))
        if (tid < PR * HH) {
            int g = tid >> 2, h = tid & 3;
            const int* mrow = mbuf + g * TT;
            float sbh = sb[h];
            float vs[TT]; float m = -1e30f;
#pragma unroll
            for (int t = 0; t < TT; ++t) {
                float s = scf[(g * TT + t) * 5 + h] * 0.125f + sbh;
                s = mrow[t] ? s : -1e9f;
                vs[t] = s; m = fmaxf(m, s);
            }
            float sum = 0.f;
#pragma unroll
            for (int t = 0; t < TT; ++t) { float e = __expf(vs[t] - m); vs[t] = e; sum += e; }
            float inv = 1.f / sum;
#pragma unroll
            for (int t = 0; t < TT; ++t) aw4[(g * TT + t) * 4 + h] = vs[t] * inv;
            if (h == 0) {
                int vvv = 0;
#pragma unroll
                for (int t = 0; t < TT; ++t) vvv |= mrow[t];
                vldf[p * PR + g] = vvv ? 1.f : 0.f;
            }
        }
        __syncthreads();
        // ---- xbar from REGISTER fp32 x, write hi/lo bf16 (overwrites xsl region — xsl dead)
#pragma unroll
        for (int gi = 0; gi < 2; ++gi) {
            const int g = gq2 * 2 + gi;
            float am[HH][4];
#pragma unroll
            for (int h = 0; h < HH; ++h)
#pragma unroll
                for (int c = 0; c < 4; ++c) am[h][c] = 0.f;
#pragma unroll
            for (int t = 0; t < TT; ++t) {
                float4 xvv = xv[gi][t];
                float4 awv = *(const float4*)(aw4 + (g * TT + t) * 4);
                am[0][0] += awv.x * xvv.x; am[0][1] += awv.x * xvv.y;
                am[0][2] += awv.x * xvv.z; am[0][3] += awv.x * xvv.w;
                am[1][0] += awv.y * xvv.x; am[1][1] += awv.y * xvv.y;
                am[1][2] += awv.y * xvv.z; am[1][3] += awv.y * xvv.w;
                am[2][0] += awv.z * xvv.x; am[2][1] += awv.z * xvv.y;
                am[2][2] += awv.z * xvv.z; am[2][3] += awv.z * xvv.w;
                am[3][0] += awv.w * xvv.x; am[3][1] += awv.w * xvv.y;
                am[3][2] += awv.w * xvv.z; am[3][3] += awv.w * xvv.w;
            }
#pragma unroll
            for (int h = 0; h < HH; ++h) {
                union { unsigned short u[4]; uint2 v2; } th, tl;
#pragma unroll
                for (int c = 0; c < 4; ++c) {
                    float v = am[h][c];
                    unsigned short hi = f2b(v);
                    th.u[c] = hi;
                    tl.u[c] = f2b(v - b2f(hi));
                }
                *(uint2*)(xbh + g * 1028 + h * EE + eh * 4) = th.v2;
                *(uint2*)(xbl + g * 1028 + h * EE + eh * 4) = tl.v2;
            }
        }
        __syncthreads();
        // ---- B1 (per pass): ypre rows p*8..p*8+7 = blockdiag(Wv) @ xbar + bv
        {
            const int h = wv;                   // wave == head
            f32x4 acc[4];
#pragma unroll
            for (int nt = 0; nt < 4; ++nt) acc[nt] = (f32x4){0.f, 0.f, 0.f, 0.f};
            for (int kb = 0; kb < EE; kb += 32) {
                bf16x8 ah = *(const bf16x8*)(xbh + (nl & 7) * 1028 + h * EE + kb + qd * 8);
                bf16x8 al = *(const bf16x8*)(xbl + (nl & 7) * 1028 + h * EE + kb + qd * 8);
#pragma unroll
                for (int nt = 0; nt < 4; ++nt) {
                    const int j = h * 64 + nt * 16 + nl;
                    bf16x8 bh, bl;
                    split8(wvw + (size_t)j * EE + kb + qd * 8, bh, bl);
                    acc[nt] = __builtin_amdgcn_mfma_f32_16x16x32_bf16(ah, bh, acc[nt], 0, 0, 0);
                    acc[nt] = __builtin_amdgcn_mfma_f32_16x16x32_bf16(al, bh, acc[nt], 0, 0, 0);
                    acc[nt] = __builtin_amdgcn_mfma_f32_16x16x32_bf16(ah, bl, acc[nt], 0, 0, 0);
                }
            }
            // C rows 8..15 duplicate rows 0..7 (A row = nl&7): write only qd<2
            if (qd < 2) {
#pragma unroll
                for (int nt = 0; nt < 4; ++nt) {
                    const int j = h * 64 + nt * 16 + nl;
                    const float bvj = in_proj_b[2 * EE + j];
#pragma unroll
                    for (int i = 0; i < 4; ++i) {
                        float vvv = acc[nt][i] + bvj;
                        unsigned short hi = f2b(vvv);
                        const int row = p * PR + qd * 4 + i;
                        yph[row * 260 + j] = hi;
                        ypl[row * 260 + j] = f2b(vvv - b2f(hi));
                    }
                }
            }
        }
    }
    __syncthreads();

    // ================= Stage B2: outv = out_w @ ypre + out_b  (M=16, hi/lo both) =================
    {
        f32x4 acc[4];
#pragma unroll
        for (int nt = 0; nt < 4; ++nt) acc[nt] = (f32x4){0.f, 0.f, 0.f, 0.f};
        for (int kb = 0; kb < EE; kb += 32) {
            bf16x8 ah = *(const bf16x8*)(yph + nl * 260 + kb + qd * 8);
            bf16x8 al = *(const bf16x8*)(ypl + nl * 260 + kb + qd * 8);
#pragma unroll
            for (int nt = 0; nt < 4; ++nt) {
                const int j = wv * 64 + nt * 16 + nl;
                bf16x8 bh, bl;
                split8(out_w + (size_t)j * EE + kb + qd * 8, bh, bl);
                acc[nt] = __builtin_amdgcn_mfma_f32_16x16x32_bf16(ah, bh, acc[nt], 0, 0, 0);
                acc[nt] = __builtin_amdgcn_mfma_f32_16x16x32_bf16(al, bh, acc[nt], 0, 0, 0);
                acc[nt] = __builtin_amdgcn_mfma_f32_16x16x32_bf16(ah, bl, acc[nt], 0, 0, 0);
            }
        }
#pragma unroll
        for (int nt = 0; nt < 4; ++nt) {
            const int j = wv * 64 + nt * 16 + nl;
            const float obj = out_b[j];
#pragma unroll
            for (int i = 0; i < 4; ++i)
                outv[(qd * 4 + i) * 260 + j] = acc[nt][i] + obj;
        }
    }
    __syncthreads();

    // ================= Stage C: LayerNorm -> lnh/lnl (hi/lo bf16) =================
    {
        const int g = tid >> 4, kc = tid & 15;
        float vals[16];
        float s = 0.f, ss = 0.f;
#pragma unroll
        for (int i = 0; i < 4; ++i) {
            float4 v = *(const float4*)(outv + g * 260 + kc * 16 + i * 4);
            vals[i * 4 + 0] = v.x; vals[i * 4 + 1] = v.y;
            vals[i * 4 + 2] = v.z; vals[i * 4 + 3] = v.w;
            s += v.x + v.y + v.z + v.w;
            ss += v.x * v.x + v.y * v.y + v.z * v.z + v.w * v.w;
        }
#pragma unroll
        for (int d = 8; d; d >>= 1) { s += __shfl_xor(s, d, 64); ss += __shfl_xor(ss, d, 64); }
        float mu = s * (1.f / EE);
        float var = ss * (1.f / EE) - mu * mu;
        float rstd = rsqrtf(var + 1e-5f);
#pragma unroll
        for (int i = 0; i < 16; i += 2) {
            int j = kc * 16 + i;
            float2 gg = *(const float2*)(ln_g + j);
            float2 bb = *(const float2*)(ln_b + j);
            float o0 = (vals[i]     - mu) * rstd * gg.x + bb.x;
            float o1 = (vals[i + 1] - mu) * rstd * gg.y + bb.y;
            unsigned short h0 = f2b(o0), h1 = f2b(o1);
            unsigned short l0 = f2b(o0 - b2f(h0)), l1 = f2b(o1 - b2f(h1));
            *(unsigned*)(lnh + g * 260 + j) = (unsigned)h0 | ((unsigned)h1 << 16);
            *(unsigned*)(lnl + g * 260 + j) = (unsigned)l0 | ((unsigned)l1 << 16);
        }
    }
    __syncthreads();

    // ================= Stage D: h = gelu(ln @ w1^T + b1) -> hbf (fp32) =================
    {
        f32x4 acc[2];
#pragma unroll
        for (int nt = 0; nt < 2; ++nt) acc[nt] = (f32x4){0.f, 0.f, 0.f, 0.f};
        for (int kb = 0; kb < EE; kb += 32) {
            bf16x8 ah = *(const bf16x8*)(lnh + nl * 260 + kb + qd * 8);
            bf16x8 al = *(const bf16x8*)(lnl + nl * 260 + kb + qd * 8);
#pragma unroll
            for (int nt = 0; nt < 2; ++nt) {
                const int j = wv * 32 + nt * 16 + nl;
                bf16x8 bh, bl;
                split8(w1 + (size_t)j * EE + kb + qd * 8, bh, bl);
                acc[nt] = __builtin_amdgcn_mfma_f32_16x16x32_bf16(ah, bh, acc[nt], 0, 0, 0);
                acc[nt] = __builtin_amdgcn_mfma_f32_16x16x32_bf16(al, bh, acc[nt], 0, 0, 0);
                acc[nt] = __builtin_amdgcn_mfma_f32_16x16x32_bf16(ah, bl, acc[nt], 0, 0, 0);
            }
        }
#pragma unroll
        for (int nt = 0; nt < 2; ++nt) {
            const int j = wv * 32 + nt * 16 + nl;
            const float bj = b1[j];
#pragma unroll
            for (int i = 0; i < 4; ++i) {
                float sv = acc[nt][i] + bj;
                float ge = 0.5f * sv * (1.0f + erff(sv * 0.70710678118654752f));
                hbf[(qd * 4 + i) * 132 + j] = ge;
            }
        }
    }
    __syncthreads();

    // ================= Stage E: logits = h @ w2 + b2 (fp32), masked =================
    {
        const int g = tid >> 4, j0 = (tid & 15) * 8;
        float4 ha = *(const float4*)(hbf + g * 132 + j0);
        float4 hb2 = *(const float4*)(hbf + g * 132 + j0 + 4);
        float4 wa = *(const float4*)(w2 + j0);
        float4 wb = *(const float4*)(w2 + j0 + 4);
        float part = ha.x * wa.x + ha.y * wa.y + ha.z * wa.z + ha.w * wa.w
                   + hb2.x * wb.x + hb2.y * wb.y + hb2.z * wb.z + hb2.w * wb.w;
#pragma unroll
        for (int d = 8; d; d >>= 1) part += __shfl_xor(part, d, 64);
        if ((tid & 15) == 0) out[chunk0 + g] = (part + b2[0]) * vldf[g];
    }
}

extern "C" void kernel_launch(void* const* d_in, const int* in_sizes, int n_in,
                              void* d_out, int out_size, void* d_ws, size_t ws_size,
                              hipStream_t stream) {
    const float* x         = (const float*)d_in[0];
    const int*   mask      = (const int*)d_in[1];
    const float* query     = (const float*)d_in[2];
    const float* in_proj_w = (const float*)d_in[3];
    const float* in_proj_b = (const float*)d_in[4];
    const float* out_w     = (const float*)d_in[5];
    const float* out_b     = (const float*)d_in[6];
    const float* ln_g      = (const float*)d_in[7];
    const float* ln_b      = (const float*)d_in[8];
    const float* w1        = (const float*)d_in[9];
    const float* b1        = (const float*)d_in[10];
    const float* w2        = (const float*)d_in[11];
    const float* b2        = (const float*)d_in[12];
    float* out = (float*)d_out;
    unsigned char* ws = (unsigned char*)d_ws;

    const int BN = out_size;                  // 32768

    setup_q<<<1, NTHREADS, 0, stream>>>(query, in_proj_w, in_proj_b, ws);
    fused_head_kernel<<<BN / RB, NTHREADS, 0, stream>>>(
        x, mask, in_proj_w, in_proj_b, out_w, out_b, ln_g, ln_b, w1, b1, w2, b2, ws, out);
}

// Round 4
// 532.962 us; speedup vs baseline: 1.0143x; 1.0143x over previous
//
#include <hip/hip_runtime.h>
#include <math.h>

// B=64, N=512, T=6, H=4, E=256, hd=64 ; BN=32768 chunks
#define TT 6
#define HH 4
#define EE 256
#define RB 16            // chunks per block
#define PR 8             // chunks per phase-A pass
#define NTHREADS 256

typedef __attribute__((ext_vector_type(8))) short bf16x8;
typedef __attribute__((ext_vector_type(4))) float f32x4;

__device__ __forceinline__ unsigned short f2b(float f) {
    union { float f; unsigned u; } v; v.f = f;
    unsigned u = v.u + 0x7fffu + ((v.u >> 16) & 1u);
    return (unsigned short)(u >> 16);
}
__device__ __forceinline__ float b2f(unsigned short s) {
    union { unsigned u; float f; } v; v.u = ((unsigned)s) << 16;
    return v.f;
}
// Truncation hi/lo split: hi = top 16 bits, lo = trunc-bf16(v - hi).
// |err| <= 2^-16 |v| — cheap (and+sub+shift per element).
__device__ __forceinline__ void split1(float v, unsigned short& h, unsigned short& l) {
    union { float f; unsigned u; } t; t.f = v;
    h = (unsigned short)(t.u >> 16);
    union { float f; unsigned u; } m; m.u = t.u & 0xffff0000u;
    union { float f; unsigned u; } r; r.f = v - m.f;
    l = (unsigned short)(r.u >> 16);
}

// Split 8 contiguous fp32 into (hi, lo) bf16x8 fragments (truncation split).
__device__ __forceinline__ void split8(const float* __restrict__ p,
                                       bf16x8& hi, bf16x8& lo) {
    float4 a = *(const float4*)p;
    float4 b = *(const float4*)(p + 4);
    float f[8] = {a.x, a.y, a.z, a.w, b.x, b.y, b.z, b.w};
    union { unsigned short s[8]; bf16x8 v; } H, L;
#pragma unroll
    for (int i = 0; i < 8; ++i) split1(f[i], H.s[i], L.s[i]);
    hi = H.v; lo = L.v;
}

// ---------------- workspace layout (bytes) ----------------
//   swt_hi [4][256] bf16 @ 0     (score weights, hi)
//   swt_lo [4][256] bf16 @ 2048  (score weights, lo)
//   sb     [4]  f32      @ 4096  (q_h . bk_h)
//   qv     [256] f32     @ 4112  (q vector for setup_swt)
//   total 5136 bytes — tiny, no OOB risk.
#define SWTH_OFF 0
#define SWTL_OFF 2048
#define SB_OFF   4096
#define QV_OFF   4112

// ---- setup 1: q = query @ Wq^T + bq ; sb[h] = q_h . bk_h  (1 block, ILP-unrolled) ----
__global__ void setup_q(const float* __restrict__ query,
                        const float* __restrict__ in_proj_w,
                        const float* __restrict__ in_proj_b,
                        unsigned char* __restrict__ ws)
{
    __shared__ float qs[EE];
    float* sb = (float*)(ws + SB_OFF);
    float* qv = (float*)(ws + QV_OFF);
    const int tid = threadIdx.x;
    float a0 = 0.f, a1 = 0.f, a2 = 0.f, a3 = 0.f;
    const float* row = in_proj_w + (size_t)tid * EE;
#pragma unroll
    for (int e = 0; e < EE; e += 16) {
        float4 w0 = *(const float4*)(row + e);
        float4 q0 = *(const float4*)(query + e);
        float4 w1v = *(const float4*)(row + e + 4);
        float4 q1 = *(const float4*)(query + e + 4);
        float4 w2v = *(const float4*)(row + e + 8);
        float4 q2 = *(const float4*)(query + e + 8);
        float4 w3v = *(const float4*)(row + e + 12);
        float4 q3 = *(const float4*)(query + e + 12);
        a0 += w0.x * q0.x + w0.y * q0.y + w0.z * q0.z + w0.w * q0.w;
        a1 += w1v.x * q1.x + w1v.y * q1.y + w1v.z * q1.z + w1v.w * q1.w;
        a2 += w2v.x * q2.x + w2v.y * q2.y + w2v.z * q2.z + w2v.w * q2.w;
        a3 += w3v.x * q3.x + w3v.y * q3.y + w3v.z * q3.z + w3v.w * q3.w;
    }
    float acc = in_proj_b[tid] + ((a0 + a1) + (a2 + a3));
    qs[tid] = acc;
    qv[tid] = acc;
    __syncthreads();
    if (tid < HH) {
        float s0 = 0.f, s1 = 0.f, s2 = 0.f, s3 = 0.f;
        const float* bk = in_proj_b + EE + tid * 64;
        const float* qh = qs + tid * 64;
#pragma unroll
        for (int d = 0; d < 64; d += 4) {
            s0 += qh[d] * bk[d];     s1 += qh[d + 1] * bk[d + 1];
            s2 += qh[d + 2] * bk[d + 2]; s3 += qh[d + 3] * bk[d + 3];
        }
        sb[tid] = (s0 + s1) + (s2 + s3);
    }
}

// ---- setup 2: swt[n][k] = sum_d q[n*64+d] * Wk[n*64+d][k]  (4 blocks, one per head) ----
__global__ void setup_swt(const float* __restrict__ in_proj_w,
                          unsigned char* __restrict__ ws)
{
    __shared__ float qh[64];
    unsigned short* swth = (unsigned short*)(ws + SWTH_OFF);
    unsigned short* swtl = (unsigned short*)(ws + SWTL_OFF);
    const float* qv = (const float*)(ws + QV_OFF);
    const int n = blockIdx.x;
    const int tid = threadIdx.x;
    if (tid < 64) qh[tid] = qv[n * 64 + tid];
    __syncthreads();
    const float* W = in_proj_w + (size_t)(EE + n * 64) * EE;   // Wk rows for head n
    float a0 = 0.f, a1 = 0.f, a2 = 0.f, a3 = 0.f;
#pragma unroll
    for (int d = 0; d < 64; d += 4) {
        a0 += qh[d]     * W[(size_t)d * EE + tid];
        a1 += qh[d + 1] * W[(size_t)(d + 1) * EE + tid];
        a2 += qh[d + 2] * W[(size_t)(d + 2) * EE + tid];
        a3 += qh[d + 3] * W[(size_t)(d + 3) * EE + tid];
    }
    float a = (a0 + a1) + (a2 + a3);
    unsigned short h = f2b(a);                 // RN hi here (free, setup-time)
    swth[n * EE + tid] = h;
    swtl[n * EE + tid] = f2b(a - b2f(h));
}

// ---------------- main fused kernel ----------------
// LDS pool layout (bytes):
#define XS_OFF   0        // xs   [48][260] bf16 = 24960 (x hi; phase A, dead after scores of last pass)
#define XBH_OFF  24960    // xb8h [8][1028] bf16 = 16448 (per-pass xbar hi)
#define XBL_OFF  41408    // xb8l [8][1028] bf16 = 16448 (per-pass xbar lo)
#define YPH_OFF  57856    // yph  [16][260] bf16 = 8320  (ypre hi, persists B1->B2)
#define YPL_OFF  66176    // ypl  [16][260] bf16 = 8320
#define SCF_OFF  74496    // scf  [48][5] f32 = 960
#define AW_OFF   75456    // aw4  [8][6][4] f32 = 768
#define VAL_OFF  76224    // validf [16] f32 = 64
#define MB_OFF   76288    // mbuf [48] int = 192
#define POOL_SZ  76480
// aliases:
//   xsl (x lo, [48][260] bf16 = 24960) aliases XBH..XBL region (24960..49920 < 57856):
//     live load->scores, while xbh/xbl live xbar->B1 (2 barriers apart). safe.
#define XSL_OFF  24960
// after phase A:
#define OUTV_OFF 0        // outv [16][260] f32 = 16640 (xs region)
#define LNH_OFF  24960    // lnh  [16][260] bf16 = 8320 (xbh region)
#define LNL_OFF  33280    // lnl  [16][260] bf16 = 8320
#define HB_OFF   41600    // hbf  [16][132] f32 = 8448  (ends 50048, xbl region)

__global__ __launch_bounds__(NTHREADS, 2)
void fused_head_kernel(const float* __restrict__ x,
                       const int* __restrict__ mask,
                       const float* __restrict__ in_proj_w,
                       const float* __restrict__ in_proj_b,
                       const float* __restrict__ out_w,
                       const float* __restrict__ out_b,
                       const float* __restrict__ ln_g,
                       const float* __restrict__ ln_b,
                       const float* __restrict__ w1,
                       const float* __restrict__ b1,
                       const float* __restrict__ w2,
                       const float* __restrict__ b2,
                       const unsigned char* __restrict__ ws,
                       float* __restrict__ out)
{
    __shared__ __align__(16) unsigned char pool[POOL_SZ];
    unsigned short* xs   = (unsigned short*)(pool + XS_OFF);
    unsigned short* xsl  = (unsigned short*)(pool + XSL_OFF);
    unsigned short* xbh  = (unsigned short*)(pool + XBH_OFF);
    unsigned short* xbl  = (unsigned short*)(pool + XBL_OFF);
    unsigned short* yph  = (unsigned short*)(pool + YPH_OFF);
    unsigned short* ypl  = (unsigned short*)(pool + YPL_OFF);
    float*          scf  = (float*)(pool + SCF_OFF);
    float*          aw4  = (float*)(pool + AW_OFF);
    float*          vldf = (float*)(pool + VAL_OFF);
    int*            mbuf = (int*)(pool + MB_OFF);
    float*          outv = (float*)(pool + OUTV_OFF);
    unsigned short* lnh  = (unsigned short*)(pool + LNH_OFF);
    unsigned short* lnl  = (unsigned short*)(pool + LNL_OFF);
    float*          hbf  = (float*)(pool + HB_OFF);

    const unsigned short* swth = (const unsigned short*)(ws + SWTH_OFF);
    const unsigned short* swtl = (const unsigned short*)(ws + SWTL_OFF);
    const float*          sb   = (const float*)(ws + SB_OFF);
    const float*          wvw  = in_proj_w + (size_t)(2 * EE) * EE;  // Wv (fp32)

    const int tid = threadIdx.x;
    const int wv  = tid >> 6;
    const int ln  = tid & 63;
    const int qd  = ln >> 4;        // quad 0..3
    const int nl  = ln & 15;        // m/n lane 0..15
    const int eh  = tid & 63;       // e-column group (e = eh*4) for load/xbar
    const int gq2 = tid >> 6;       // chunk-pair group for load/xbar
    const int chunk0 = blockIdx.x * RB;

    float4 xv[2][TT];               // this thread's fp32 x slice (2 chunks x 6 t x 4 cols)

    // ================= Phase A + per-pass B1 (two passes of 8 chunks) =================
    for (int p = 0; p < 2; ++p) {
        const int c0 = chunk0 + p * PR;
        __syncthreads();   // xs/xsl / mbuf / aw4 / scf / xb8 reuse safe
        if (tid < PR * TT) mbuf[tid] = mask[(size_t)c0 * TT + tid];
        // ---- load x -> registers (fp32) and xs/xsl (hi/lo bf16 for score MFMA)
        const float* xp = x + (size_t)c0 * (TT * EE);
#pragma unroll
        for (int gi = 0; gi < 2; ++gi) {
#pragma unroll
            for (int t = 0; t < TT; ++t) {
                const int r = (gq2 * 2 + gi) * TT + t;
                float4 v = *(const float4*)(xp + r * EE + eh * 4);
                xv[gi][t] = v;
                union { unsigned short u[4]; uint2 v2; } th, tl;
                split1(v.x, th.u[0], tl.u[0]);
                split1(v.y, th.u[1], tl.u[1]);
                split1(v.z, th.u[2], tl.u[2]);
                split1(v.w, th.u[3], tl.u[3]);
                *(uint2*)(xs  + r * 260 + eh * 4) = th.v2;
                *(uint2*)(xsl + r * 260 + eh * 4) = tl.v2;
            }
        }
        __syncthreads();
        // ---- scores MFMA (hi/lo both sides): S[(g,t)][h] ; 3 M-tiles over 48 rows
        if (wv < 3) {
            const int mt = wv;
            f32x4 acc = {0.f, 0.f, 0.f, 0.f};
            for (int kb = 0; kb < EE; kb += 32) {
                bf16x8 ah = *(const bf16x8*)(xs  + (mt * 16 + nl) * 260 + kb + qd * 8);
                bf16x8 al = *(const bf16x8*)(xsl + (mt * 16 + nl) * 260 + kb + qd * 8);
                bf16x8 bh = *(const bf16x8*)(swth + (nl & 3) * EE + kb + qd * 8);
                bf16x8 bl = *(const bf16x8*)(swtl + (nl & 3) * EE + kb + qd * 8);
                acc = __builtin_amdgcn_mfma_f32_16x16x32_bf16(ah, bh, acc, 0, 0, 0);
                acc = __builtin_amdgcn_mfma_f32_16x16x32_bf16(al, bh, acc, 0, 0, 0);
                acc = __builtin_amdgcn_mfma_f32_16x16x32_bf16(ah, bl, acc, 0, 0, 0);
            }
            if (nl < HH) {
#pragma unroll
                for (int i = 0; i < 4; ++i)
                    scf[(mt * 16 + qd * 4 + i) * 5 + nl] = acc[i];
            }
        }
        __syncthreads();
        // ---- softmax (tid<32: (g,h))
        if (tid < PR * HH) {
            int g = tid >> 2, h = tid & 3;
            const int* mrow = mbuf + g * TT;
            float sbh = sb[h];
            float vs[TT]; float m = -1e30f;
#pragma unroll
            for (int t = 0; t < TT; ++t) {
                float s = scf[(g * TT + t) * 5 + h] * 0.125f + sbh;
                s = mrow[t] ? s : -1e9f;
                vs[t] = s; m = fmaxf(m, s);
            }
            float sum = 0.f;
#pragma unroll
            for (int t = 0; t < TT; ++t) { float e = __expf(vs[t] - m); vs[t] = e; sum += e; }
            float inv = 1.f / sum;
#pragma unroll
            for (int t = 0; t < TT; ++t) aw4[(g * TT + t) * 4 + h] = vs[t] * inv;
            if (h == 0) {
                int vvv = 0;
#pragma unroll
                for (int t = 0; t < TT; ++t) vvv |= mrow[t];
                vldf[p * PR + g] = vvv ? 1.f : 0.f;
            }
        }
        __syncthreads();
        // ---- xbar from REGISTER fp32 x, write hi/lo bf16 (overwrites xsl region — xsl dead)
#pragma unroll
        for (int gi = 0; gi < 2; ++gi) {
            const int g = gq2 * 2 + gi;
            float am[HH][4];
#pragma unroll
            for (int h = 0; h < HH; ++h)
#pragma unroll
                for (int c = 0; c < 4; ++c) am[h][c] = 0.f;
#pragma unroll
            for (int t = 0; t < TT; ++t) {
                float4 xvv = xv[gi][t];
                float4 awv = *(const float4*)(aw4 + (g * TT + t) * 4);
                am[0][0] += awv.x * xvv.x; am[0][1] += awv.x * xvv.y;
                am[0][2] += awv.x * xvv.z; am[0][3] += awv.x * xvv.w;
                am[1][0] += awv.y * xvv.x; am[1][1] += awv.y * xvv.y;
                am[1][2] += awv.y * xvv.z; am[1][3] += awv.y * xvv.w;
                am[2][0] += awv.z * xvv.x; am[2][1] += awv.z * xvv.y;
                am[2][2] += awv.z * xvv.z; am[2][3] += awv.z * xvv.w;
                am[3][0] += awv.w * xvv.x; am[3][1] += awv.w * xvv.y;
                am[3][2] += awv.w * xvv.z; am[3][3] += awv.w * xvv.w;
            }
#pragma unroll
            for (int h = 0; h < HH; ++h) {
                union { unsigned short u[4]; uint2 v2; } th, tl;
#pragma unroll
                for (int c = 0; c < 4; ++c) split1(am[h][c], th.u[c], tl.u[c]);
                *(uint2*)(xbh + g * 1028 + h * EE + eh * 4) = th.v2;
                *(uint2*)(xbl + g * 1028 + h * EE + eh * 4) = tl.v2;
            }
        }
        __syncthreads();
        // ---- B1 (per pass): ypre rows p*8..p*8+7 = blockdiag(Wv) @ xbar + bv
        {
            const int h = wv;                   // wave == head
            f32x4 acc[4];
#pragma unroll
            for (int nt = 0; nt < 4; ++nt) acc[nt] = (f32x4){0.f, 0.f, 0.f, 0.f};
            for (int kb = 0; kb < EE; kb += 32) {
                bf16x8 ah = *(const bf16x8*)(xbh + (nl & 7) * 1028 + h * EE + kb + qd * 8);
                bf16x8 al = *(const bf16x8*)(xbl + (nl & 7) * 1028 + h * EE + kb + qd * 8);
#pragma unroll
                for (int nt = 0; nt < 4; ++nt) {
                    const int j = h * 64 + nt * 16 + nl;
                    bf16x8 bh, bl;
                    split8(wvw + (size_t)j * EE + kb + qd * 8, bh, bl);
                    acc[nt] = __builtin_amdgcn_mfma_f32_16x16x32_bf16(ah, bh, acc[nt], 0, 0, 0);
                    acc[nt] = __builtin_amdgcn_mfma_f32_16x16x32_bf16(al, bh, acc[nt], 0, 0, 0);
                    acc[nt] = __builtin_amdgcn_mfma_f32_16x16x32_bf16(ah, bl, acc[nt], 0, 0, 0);
                }
            }
            // C rows 8..15 duplicate rows 0..7 (A row = nl&7): write only qd<2
            if (qd < 2) {
#pragma unroll
                for (int nt = 0; nt < 4; ++nt) {
                    const int j = h * 64 + nt * 16 + nl;
                    const float bvj = in_proj_b[2 * EE + j];
#pragma unroll
                    for (int i = 0; i < 4; ++i) {
                        float vvv = acc[nt][i] + bvj;
                        const int row = p * PR + qd * 4 + i;
                        unsigned short hh, ll;
                        split1(vvv, hh, ll);
                        yph[row * 260 + j] = hh;
                        ypl[row * 260 + j] = ll;
                    }
                }
            }
        }
    }
    __syncthreads();

    // ================= Stage B2: outv = out_w @ ypre + out_b  (M=16, hi/lo both) =================
    {
        f32x4 acc[4];
#pragma unroll
        for (int nt = 0; nt < 4; ++nt) acc[nt] = (f32x4){0.f, 0.f, 0.f, 0.f};
        for (int kb = 0; kb < EE; kb += 32) {
            bf16x8 ah = *(const bf16x8*)(yph + nl * 260 + kb + qd * 8);
            bf16x8 al = *(const bf16x8*)(ypl + nl * 260 + kb + qd * 8);
#pragma unroll
            for (int nt = 0; nt < 4; ++nt) {
                const int j = wv * 64 + nt * 16 + nl;
                bf16x8 bh, bl;
                split8(out_w + (size_t)j * EE + kb + qd * 8, bh, bl);
                acc[nt] = __builtin_amdgcn_mfma_f32_16x16x32_bf16(ah, bh, acc[nt], 0, 0, 0);
                acc[nt] = __builtin_amdgcn_mfma_f32_16x16x32_bf16(al, bh, acc[nt], 0, 0, 0);
                acc[nt] = __builtin_amdgcn_mfma_f32_16x16x32_bf16(ah, bl, acc[nt], 0, 0, 0);
            }
        }
#pragma unroll
        for (int nt = 0; nt < 4; ++nt) {
            const int j = wv * 64 + nt * 16 + nl;
            const float obj = out_b[j];
#pragma unroll
            for (int i = 0; i < 4; ++i)
                outv[(qd * 4 + i) * 260 + j] = acc[nt][i] + obj;
        }
    }
    __syncthreads();

    // ================= Stage C: LayerNorm -> lnh/lnl (hi/lo bf16) =================
    {
        const int g = tid >> 4, kc = tid & 15;
        float vals[16];
        float s = 0.f, ss = 0.f;
#pragma unroll
        for (int i = 0; i < 4; ++i) {
            float4 v = *(const float4*)(outv + g * 260 + kc * 16 + i * 4);
            vals[i * 4 + 0] = v.x; vals[i * 4 + 1] = v.y;
            vals[i * 4 + 2] = v.z; vals[i * 4 + 3] = v.w;
            s += v.x + v.y + v.z + v.w;
            ss += v.x * v.x + v.y * v.y + v.z * v.z + v.w * v.w;
        }
#pragma unroll
        for (int d = 8; d; d >>= 1) { s += __shfl_xor(s, d, 64); ss += __shfl_xor(ss, d, 64); }
        float mu = s * (1.f / EE);
        float var = ss * (1.f / EE) - mu * mu;
        float rstd = rsqrtf(var + 1e-5f);
#pragma unroll
        for (int i = 0; i < 16; i += 2) {
            int j = kc * 16 + i;
            float2 gg = *(const float2*)(ln_g + j);
            float2 bb = *(const float2*)(ln_b + j);
            float o0 = (vals[i]     - mu) * rstd * gg.x + bb.x;
            float o1 = (vals[i + 1] - mu) * rstd * gg.y + bb.y;
            unsigned short h0, l0, h1, l1;
            split1(o0, h0, l0); split1(o1, h1, l1);
            *(unsigned*)(lnh + g * 260 + j) = (unsigned)h0 | ((unsigned)h1 << 16);
            *(unsigned*)(lnl + g * 260 + j) = (unsigned)l0 | ((unsigned)l1 << 16);
        }
    }
    __syncthreads();

    // ================= Stage D: h = gelu(ln @ w1^T + b1) -> hbf (fp32) =================
    {
        f32x4 acc[2];
#pragma unroll
        for (int nt = 0; nt < 2; ++nt) acc[nt] = (f32x4){0.f, 0.f, 0.f, 0.f};
        for (int kb = 0; kb < EE; kb += 32) {
            bf16x8 ah = *(const bf16x8*)(lnh + nl * 260 + kb + qd * 8);
            bf16x8 al = *(const bf16x8*)(lnl + nl * 260 + kb + qd * 8);
#pragma unroll
            for (int nt = 0; nt < 2; ++nt) {
                const int j = wv * 32 + nt * 16 + nl;
                bf16x8 bh, bl;
                split8(w1 + (size_t)j * EE + kb + qd * 8, bh, bl);
                acc[nt] = __builtin_amdgcn_mfma_f32_16x16x32_bf16(ah, bh, acc[nt], 0, 0, 0);
                acc[nt] = __builtin_amdgcn_mfma_f32_16x16x32_bf16(al, bh, acc[nt], 0, 0, 0);
                acc[nt] = __builtin_amdgcn_mfma_f32_16x16x32_bf16(ah, bl, acc[nt], 0, 0, 0);
            }
        }
#pragma unroll
        for (int nt = 0; nt < 2; ++nt) {
            const int j = wv * 32 + nt * 16 + nl;
            const float bj = b1[j];
#pragma unroll
            for (int i = 0; i < 4; ++i) {
                float sv = acc[nt][i] + bj;
                float ge = 0.5f * sv * (1.0f + erff(sv * 0.70710678118654752f));
                hbf[(qd * 4 + i) * 132 + j] = ge;
            }
        }
    }
    __syncthreads();

    // ================= Stage E: logits = h @ w2 + b2 (fp32), masked =================
    {
        const int g = tid >> 4, j0 = (tid & 15) * 8;
        float4 ha = *(const float4*)(hbf + g * 132 + j0);
        float4 hb2 = *(const float4*)(hbf + g * 132 + j0 + 4);
        float4 wa = *(const float4*)(w2 + j0);
        float4 wb = *(const float4*)(w2 + j0 + 4);
        float part = ha.x * wa.x + ha.y * wa.y + ha.z * wa.z + ha.w * wa.w
                   + hb2.x * wb.x + hb2.y * wb.y + hb2.z * wb.z + hb2.w * wb.w;
#pragma unroll
        for (int d = 8; d; d >>= 1) part += __shfl_xor(part, d, 64);
        if ((tid & 15) == 0) out[chunk0 + g] = (part + b2[0]) * vldf[g];
    }
}

extern "C" void kernel_launch(void* const* d_in, const int* in_sizes, int n_in,
                              void* d_out, int out_size, void* d_ws, size_t ws_size,
                              hipStream_t stream) {
    const float* x         = (const float*)d_in[0];
    const int*   mask      = (const int*)d_in[1];
    const float* query     = (const float*)d_in[2];
    const float* in_proj_w = (const float*)d_in[3];
    const float* in_proj_b = (const float*)d_in[4];
    const float* out_w     = (const float*)d_in[5];
    const float* out_b     = (const float*)d_in[6];
    const float* ln_g      = (const float*)d_in[7];
    const float* ln_b      = (const float*)d_in[8];
    const float* w1        = (const float*)d_in[9];
    const float* b1        = (const float*)d_in[10];
    const float* w2        = (const float*)d_in[11];
    const float* b2        = (const float*)d_in[12];
    float* out = (float*)d_out;
    unsigned char* ws = (unsigned char*)d_ws;

    const int BN = out_size;                  // 32768

    setup_q<<<1, NTHREADS, 0, stream>>>(query, in_proj_w, in_proj_b, ws);
    setup_swt<<<HH, NTHREADS, 0, stream>>>(in_proj_w, ws);
    fused_head_kernel<<<BN / RB, NTHREADS, 0, stream>>>(
        x, mask, in_proj_w, in_proj_b, out_w, out_b, ln_g, ln_b, w1, b1, w2, b2, ws, out);
}